// Round 32
// baseline (805.457 us; speedup 1.0000x reference)
//
#include <hip/hip_runtime.h>
#include <hip/hip_bf16.h>
#include <math.h>

// ---------------------------------------------------------------------------
// HMABottleneck: B=4, C=512, H=W=16, DI=1024, K=4 dirs, N=16 states, R=32
// Round 32: im2col vectorized x8 (one uint4 store / thread, incremental
// (ci,q) update; 8x fewer threads, full write coalescing). Bit-identical.
// Rest = r31 (776 us).
// ---------------------------------------------------------------------------

constexpr int B_  = 4;
constexpr int C_  = 512;
constexpr int DI_ = 1024;
constexpr int K_  = 4;
constexpr int N_  = 16;
constexpr int R_  = 32;
constexpr int KC9 = C_ * 9;                   // conv GEMM K dim = 4608
constexpr int KSPL = 4;                       // split-K factor (all split GEMMs)
constexpr int KSEG = KC9 / KSPL;              // 1152
constexpr float BNS_ = 0.9999950000374997f;   // 1/sqrt(1+1e-5)

typedef __attribute__((ext_vector_type(8))) short bf16x8;
typedef __attribute__((ext_vector_type(4))) float f32x4;

__device__ inline float geluf(float x) {
    return 0.5f * x * (1.0f + erff(x * 0.70710678118654752f));
}
__device__ inline float siluf(float x) {
    return x / (1.0f + expf(-x));
}
__device__ inline float softplusf(float x) {
    return fmaxf(x, 0.0f) + log1pf(expf(-fabsf(x)));
}
// fast variants: scan kernel only (args bounded, abs budget has 3x headroom)
__device__ inline float softplus_fast(float x) {
    return fmaxf(x, 0.0f) + __logf(1.0f + __expf(-fabsf(x)));
}
__device__ inline short bf16s(float x) {
    __hip_bfloat16 h = __float2bfloat16(x);
    return *reinterpret_cast<short*>(&h);
}

__device__ inline float blockReduceSum(float v, float* sd) {
    int tid = threadIdx.x;
    sd[tid] = v; __syncthreads();
    for (int s = blockDim.x / 2; s > 0; s >>= 1) {
        if (tid < s) sd[tid] += sd[tid + s];
        __syncthreads();
    }
    float r = sd[0]; __syncthreads();
    return r;
}

// --------------------------- LN over channels (NCHW -> (B*L, C)) -----------
__global__ void k_ln_nchw(const float* __restrict__ x, const float* __restrict__ w,
                          const float* __restrict__ b, float* __restrict__ out,
                          int L, float eps) {
    int row = blockIdx.x;            // b*L + l
    int bb = row / L, l = row % L;
    __shared__ float sd[256];
    __shared__ float srow[C_];
    const float* xp = x + (size_t)bb * C_ * L + l;
    float sum = 0.f;
    for (int c = threadIdx.x; c < C_; c += 256) { float v = xp[(size_t)c * L]; srow[c] = v; sum += v; }
    sum = blockReduceSum(sum, sd);
    float mu = sum / C_;
    float vs = 0.f;
    for (int c = threadIdx.x; c < C_; c += 256) { float d = srow[c] - mu; vs += d * d; }
    vs = blockReduceSum(vs, sd);
    float rstd = rsqrtf(vs / C_ + eps);
    float* op = out + (size_t)row * C_;
    for (int c = threadIdx.x; c < C_; c += 256) op[c] = (srow[c] - mu) * rstd * w[c] + b[c];
}

// --------------------------- bf16 MFMA GEMM: out = A (M,K) * Bw(N,K)^T -----
template <int EPI>
__global__ void k_gemm_mfma(const float* __restrict__ A, const float* __restrict__ Bw,
                            float* __restrict__ Cout, int M, int Nn, int Kk,
                            const float* __restrict__ Res, int L) {
    const int BK = 32, PITCH = 40;
    __shared__ short As[64 * PITCH];
    __shared__ short Bs[64 * PITCH];
    int m0 = blockIdx.y * 64, n0 = blockIdx.x * 64;
    int tid = threadIdx.x;
    int wv = tid >> 6, lane = tid & 63;
    int frow = lane & 15, kg = lane >> 4;
    f32x4 acc[4];
#pragma unroll
    for (int t = 0; t < 4; t++) acc[t] = (f32x4){0.f, 0.f, 0.f, 0.f};

    int sr = tid >> 2;
    int kq = (tid & 3) * 4;
    for (int k0 = 0; k0 < Kk; k0 += BK) {
        const float* ap = A + (size_t)(m0 + sr) * Kk + k0;
        const float* bp = Bw + (size_t)(n0 + sr) * Kk + k0;
        float4 a1 = *reinterpret_cast<const float4*>(ap + kq);
        float4 a2 = *reinterpret_cast<const float4*>(ap + kq + 16);
        float4 b1 = *reinterpret_cast<const float4*>(bp + kq);
        float4 b2 = *reinterpret_cast<const float4*>(bp + kq + 16);
        short* ad = &As[sr * PITCH + kq];
        ad[0] = bf16s(a1.x); ad[1] = bf16s(a1.y); ad[2] = bf16s(a1.z); ad[3] = bf16s(a1.w);
        ad[16] = bf16s(a2.x); ad[17] = bf16s(a2.y); ad[18] = bf16s(a2.z); ad[19] = bf16s(a2.w);
        short* bd = &Bs[sr * PITCH + kq];
        bd[0] = bf16s(b1.x); bd[1] = bf16s(b1.y); bd[2] = bf16s(b1.z); bd[3] = bf16s(b1.w);
        bd[16] = bf16s(b2.x); bd[17] = bf16s(b2.y); bd[18] = bf16s(b2.z); bd[19] = bf16s(b2.w);
        __syncthreads();
        bf16x8 afrag = *reinterpret_cast<const bf16x8*>(&As[(wv * 16 + frow) * PITCH + kg * 8]);
#pragma unroll
        for (int t = 0; t < 4; t++) {
            bf16x8 bfrag = *reinterpret_cast<const bf16x8*>(&Bs[(t * 16 + frow) * PITCH + kg * 8]);
            acc[t] = __builtin_amdgcn_mfma_f32_16x16x32_bf16(afrag, bfrag, acc[t], 0, 0, 0);
        }
        __syncthreads();
    }

    int orow = kg * 4;
#pragma unroll
    for (int t = 0; t < 4; t++) {
#pragma unroll
        for (int r = 0; r < 4; r++) {
            int m = m0 + wv * 16 + orow + r;
            int n = n0 + t * 16 + frow;
            if (EPI == 0) {
                Cout[(size_t)m * Nn + n] = acc[t][r];
            } else {
                int bb = m / L, l = m % L;
                size_t o = ((size_t)bb * C_ + n) * L + l;
                Cout[o] = Res[o] + acc[t][r];
            }
        }
    }
}

// --------------------------- split-K partial GEMM (f32 inputs) -------------
__global__ void k_gemm_part(const float* __restrict__ A, const float* __restrict__ Bw,
                            float* __restrict__ partial, int M, int Nn, int Kk) {
    const int BK = 32, PITCH = 40;
    __shared__ short As[64 * PITCH];
    __shared__ short Bs[64 * PITCH];
    int m0 = blockIdx.y * 64, n0 = blockIdx.x * 64;
    int s = blockIdx.z;
    int tid = threadIdx.x;
    int wv = tid >> 6, lane = tid & 63;
    int frow = lane & 15, kg = lane >> 4;
    f32x4 acc[4];
#pragma unroll
    for (int t = 0; t < 4; t++) acc[t] = (f32x4){0.f, 0.f, 0.f, 0.f};

    int sr = tid >> 2;
    int kq = (tid & 3) * 4;
    int kseg = Kk / KSPL;
    int kbeg = s * kseg;
    for (int k0 = kbeg; k0 < kbeg + kseg; k0 += BK) {
        const float* ap = A + (size_t)(m0 + sr) * Kk + k0;
        const float* bp = Bw + (size_t)(n0 + sr) * Kk + k0;
        float4 a1 = *reinterpret_cast<const float4*>(ap + kq);
        float4 a2 = *reinterpret_cast<const float4*>(ap + kq + 16);
        float4 b1 = *reinterpret_cast<const float4*>(bp + kq);
        float4 b2 = *reinterpret_cast<const float4*>(bp + kq + 16);
        short* ad = &As[sr * PITCH + kq];
        ad[0] = bf16s(a1.x); ad[1] = bf16s(a1.y); ad[2] = bf16s(a1.z); ad[3] = bf16s(a1.w);
        ad[16] = bf16s(a2.x); ad[17] = bf16s(a2.y); ad[18] = bf16s(a2.z); ad[19] = bf16s(a2.w);
        short* bd = &Bs[sr * PITCH + kq];
        bd[0] = bf16s(b1.x); bd[1] = bf16s(b1.y); bd[2] = bf16s(b1.z); bd[3] = bf16s(b1.w);
        bd[16] = bf16s(b2.x); bd[17] = bf16s(b2.y); bd[18] = bf16s(b2.z); bd[19] = bf16s(b2.w);
        __syncthreads();
        bf16x8 afrag = *reinterpret_cast<const bf16x8*>(&As[(wv * 16 + frow) * PITCH + kg * 8]);
#pragma unroll
        for (int t = 0; t < 4; t++) {
            bf16x8 bfrag = *reinterpret_cast<const bf16x8*>(&Bs[(t * 16 + frow) * PITCH + kg * 8]);
            acc[t] = __builtin_amdgcn_mfma_f32_16x16x32_bf16(afrag, bfrag, acc[t], 0, 0, 0);
        }
        __syncthreads();
    }

    int orow = kg * 4;
    float* pb = partial + (size_t)s * M * Nn;
#pragma unroll
    for (int t = 0; t < 4; t++) {
#pragma unroll
        for (int r = 0; r < 4; r++) {
            int m = m0 + wv * 16 + orow + r;
            int n = n0 + t * 16 + frow;
            pb[(size_t)m * Nn + n] = acc[t][r];
        }
    }
}

// --------------------------- outproj fin: sum partials + residual ----------
__global__ void k_outproj_fin(const float* __restrict__ partial, const float* __restrict__ res,
                              float* __restrict__ out, int L) {
    int Nn = C_;
    int total = B_ * L * Nn;
    int idx = blockIdx.x * 256 + threadIdx.x;
    if (idx >= total) return;
    int m = idx / Nn, n = idx % Nn;
    float a = 0.f;
#pragma unroll
    for (int s = 0; s < KSPL; s++) a += partial[(size_t)s * B_ * L * Nn + idx];
    int bb = m / L, l = m % L;
    size_t o = ((size_t)bb * C_ + n) * L + l;
    out[o] = res[o] + a;
}

// --------------------------- pw fin: sum partials + BN + GELU -> NCHW ------
__global__ void k_pw_fin(const float* __restrict__ partial, const float* __restrict__ bns,
                         const float* __restrict__ bnb, float* __restrict__ out,
                         int M, int L2) {
    int total = M * C_;
    int idx = blockIdx.x * 256 + threadIdx.x;
    if (idx >= total) return;
    int m = idx / C_, n = idx % C_;
    float a = 0.f;
#pragma unroll
    for (int s = 0; s < KSPL; s++) a += partial[(size_t)s * M * C_ + idx];
    int bb = m / L2, l = m % L2;
    out[((size_t)bb * C_ + n) * L2 + l] = geluf(a * (bns[n] * BNS_) + bnb[n]);
}

// --------------------------- im2col (bf16, x8 vectorized) ------------------
// r32: each thread emits 8 consecutive kidx (one uint4 store). KC9 % 8 == 0
// so the span stays within one row n; byte offset 16-aligned.
__global__ void k_im2col(const float* __restrict__ inp, short* __restrict__ ocol,
                         int H, int W) {
    int L = H * W;
    const int KQ8 = KC9 / 8;                 // 576 vec-stores per row
    int total = B_ * L * KQ8;
    int idx = blockIdx.x * 256 + threadIdx.x;
    if (idx >= total) return;
    int kb = (idx % KQ8) * 8;
    int n = idx / KQ8;
    int l = n % L; int bb = n / L;
    int h = l / W, w = l % W;
    int ci = kb / 9, q = kb % 9;
    short v[8];
#pragma unroll
    for (int j = 0; j < 8; j++) {
        int dy = q / 3, dx = q % 3;
        int hh = h + dy - 1, ww = w + dx - 1;
        float f = 0.f;
        if ((unsigned)hh < (unsigned)H && (unsigned)ww < (unsigned)W)
            f = inp[(((size_t)bb * C_ + ci) * H + hh) * W + ww];
        v[j] = bf16s(f);
        q++; if (q == 9) { q = 0; ci++; }
    }
    *reinterpret_cast<uint4*>(ocol + (size_t)n * KC9 + kb) = *reinterpret_cast<const uint4*>(v);
}

// --------------------------- conv GEMM split-K partial ---------------------
__global__ void k_gemm_conv_part(const float* __restrict__ wgt, const short* __restrict__ bcol,
                                 float* __restrict__ partial, int Nn) {
    const int BK = 32, PITCH = 40;
    __shared__ short As[64 * PITCH];
    __shared__ short Bs[64 * PITCH];
    int m0 = blockIdx.y * 64, n0 = blockIdx.x * 64;
    int s = blockIdx.z;
    int tid = threadIdx.x;
    int wv = tid >> 6, lane = tid & 63;
    int frow = lane & 15, kg = lane >> 4;
    f32x4 acc[4];
#pragma unroll
    for (int t = 0; t < 4; t++) acc[t] = (f32x4){0.f, 0.f, 0.f, 0.f};

    int sr = tid >> 2;
    int kq = (tid & 3) * 4;
    int kq8 = (tid & 3) * 8;
    int kbeg = s * KSEG;
    for (int k0 = kbeg; k0 < kbeg + KSEG; k0 += BK) {
        const float* ap = wgt + (size_t)(m0 + sr) * KC9 + k0;
        float4 a1 = *reinterpret_cast<const float4*>(ap + kq);
        float4 a2 = *reinterpret_cast<const float4*>(ap + kq + 16);
        short* ad = &As[sr * PITCH + kq];
        ad[0] = bf16s(a1.x); ad[1] = bf16s(a1.y); ad[2] = bf16s(a1.z); ad[3] = bf16s(a1.w);
        ad[16] = bf16s(a2.x); ad[17] = bf16s(a2.y); ad[18] = bf16s(a2.z); ad[19] = bf16s(a2.w);
        uint4 bv = *reinterpret_cast<const uint4*>(bcol + (size_t)(n0 + sr) * KC9 + k0 + kq8);
        *reinterpret_cast<uint4*>(&Bs[sr * PITCH + kq8]) = bv;
        __syncthreads();
        bf16x8 afrag = *reinterpret_cast<const bf16x8*>(&As[(wv * 16 + frow) * PITCH + kg * 8]);
#pragma unroll
        for (int t = 0; t < 4; t++) {
            bf16x8 bfrag = *reinterpret_cast<const bf16x8*>(&Bs[(t * 16 + frow) * PITCH + kg * 8]);
            acc[t] = __builtin_amdgcn_mfma_f32_16x16x32_bf16(afrag, bfrag, acc[t], 0, 0, 0);
        }
        __syncthreads();
    }

    int orow = kg * 4;
    float* pb = partial + (size_t)s * C_ * Nn;
#pragma unroll
    for (int t = 0; t < 4; t++) {
#pragma unroll
        for (int r = 0; r < 4; r++) {
            int m = m0 + wv * 16 + orow + r;
            int n = n0 + t * 16 + frow;
            pb[(size_t)m * Nn + n] = acc[t][r];
        }
    }
}

// --------------------------- conv fin: sum KSPL partials + epilogue --------
// CM 0: gelu(bn(a));  CM 1: gelu(bn(a)+res);  CM 2: gelu(bn(a))+res;
// CM 3: gelu(bn2(gelu(bn(a)+res)))   (resblk fin + head bn0+gelu fused)
template <int CM>
__global__ void k_conv_fin2(const float* __restrict__ partial, const float* __restrict__ bns,
                            const float* __restrict__ bnb, const float* __restrict__ res,
                            float* __restrict__ out, int Nn, int L,
                            const float* __restrict__ bns2, const float* __restrict__ bnb2) {
    int idx = blockIdx.x * 256 + threadIdx.x;    // (m, n) n fastest
    int total = C_ * Nn;
    if (idx >= total) return;
    int m = idx / Nn, n = idx % Nn;
    float a = 0.f;
#pragma unroll
    for (int s = 0; s < KSPL; s++) a += partial[(size_t)s * C_ * Nn + idx];
    int bb = n / L, l = n % L;
    size_t o = ((size_t)bb * C_ + m) * L + l;
    a = a * (bns[m] * BNS_) + bnb[m];
    if (CM == 0) out[o] = geluf(a);
    else if (CM == 1) out[o] = geluf(a + res[o]);
    else if (CM == 2) out[o] = geluf(a) + res[o];
    else {
        float v = geluf(a + res[o]);
        out[o] = geluf(v * (bns2[m] * BNS_) + bnb2[m]);
    }
}

// --------------------------- depthwise 3x3 s2 + BN + GELU -> (pixel, c) ----
__global__ void k_dwconv_s2_bn_gelu(const float* __restrict__ x, const float* __restrict__ dw,
                                    const float* __restrict__ bns, const float* __restrict__ bnb,
                                    float* __restrict__ out, int Hi, int Wi) {
    int Ho = Hi / 2, Wo = Wi / 2;
    int idx = blockIdx.x * 256 + threadIdx.x;            // (b,ho,wo,c) c fastest
    int total = B_ * C_ * Ho * Wo;
    if (idx >= total) return;
    int c = idx % C_; int t = idx / C_; int wo = t % Wo; t /= Wo; int ho = t % Ho; int bb = t / Ho;
    float acc = 0.f;
    const float* xp = x + ((size_t)bb * C_ + c) * Hi * Wi;
    const float* wp = dw + c * 9;
#pragma unroll
    for (int dy = 0; dy < 3; dy++) {
        int ih = ho * 2 + dy - 1;
        if ((unsigned)ih >= (unsigned)Hi) continue;
#pragma unroll
        for (int dx = 0; dx < 3; dx++) {
            int iw = wo * 2 + dx - 1;
            if ((unsigned)iw >= (unsigned)Wi) continue;
            acc += xp[ih * Wi + iw] * wp[dy * 3 + dx];
        }
    }
    acc = acc * (bns[c] * BNS_) + bnb[c];
    out[((size_t)(bb * Ho + ho) * Wo + wo) * C_ + c] = geluf(acc);
}

// --------------------------- depthwise 3x3 (pad1) + bias + SiLU ------------
__global__ void k_dwconv_silu(const float* __restrict__ xz, const float* __restrict__ cw,
                              const float* __restrict__ cb, float* __restrict__ xm,
                              float* __restrict__ xmT, int H, int W) {
    int L = H * W;
    int idx = blockIdx.x * 256 + threadIdx.x;            // (b, l, d) d fastest
    int total = B_ * L * DI_;
    if (idx >= total) return;
    int d = idx % DI_; int t = idx / DI_; int l = t % L; int bb = t / L;
    int h = l / W, w = l % W;
    float acc = cb[d];
    const float* wp = cw + d * 9;
#pragma unroll
    for (int dy = 0; dy < 3; dy++) {
        int hh = h + dy - 1;
        if ((unsigned)hh >= (unsigned)H) continue;
#pragma unroll
        for (int dx = 0; dx < 3; dx++) {
            int ww = w + dx - 1;
            if ((unsigned)ww >= (unsigned)W) continue;
            acc += xz[((size_t)bb * L + hh * W + ww) * (2 * DI_) + d] * wp[dy * 3 + dx];
        }
    }
    float v = siluf(acc);
    xm[idx] = v;
    xmT[((size_t)bb * DI_ + d) * L + l] = v;
}

// map (k,l) -> source flat index in row-major (h*W+w) order
__device__ inline int dir_src(int k, int l, int H, int W, int L) {
    int ll = (k >= 2) ? (L - 1 - l) : l;
    return (k & 1) ? ((ll % H) * W + ll / H) : ll;
}

// --------------------------- gather: xdbl from split-K partials ------------
__global__ void k_gather_xdbl(const float* __restrict__ tmp, float* __restrict__ xdbl,
                              int H, int W) {
    int L = H * W;
    int Nn = B_ * L;
    int total = B_ * K_ * 64 * L;
    int idx = blockIdx.x * 256 + threadIdx.x;
    if (idx >= total) return;
    int l = idx % L; int t = idx / L; int c = t % 64; t /= 64; int k = t % K_; int bb = t / K_;
    int src = dir_src(k, l, H, W, L);
    size_t col = (size_t)bb * L + src;
    float v = 0.f;
#pragma unroll
    for (int s = 0; s < KSPL; s++)
        v += tmp[((size_t)s * K_ * 64 + k * 64 + c) * Nn + col];
    xdbl[idx] = v;
}

// --------------------------- wave scan, SPL steps per lane (r28 form) ------
template <int LT>
__global__ void k_scan_wave(const float* __restrict__ xmT, const float* __restrict__ xdbl,
                            const float* __restrict__ dtw, const float* __restrict__ dtb,
                            const float* __restrict__ Alog, const float* __restrict__ Dp,
                            float* __restrict__ part, int H, int W) {
    constexpr int SPL = (LT == 256) ? 4 : 1;
    constexpr int CW  = (LT < 64) ? LT : 64;
    const int L = LT;
    int lane = threadIdx.x & 63;
    int wv = threadIdx.x >> 6;
    int blk = blockIdx.x;                // (bb, k, dq)
    const int ndq = DI_ / 4;
    int dq = blk % ndq; int t2 = blk / ndq; int k = t2 % K_; int bb = t2 / K_;
    int d = dq * 4 + wv;

    const float* wrow = dtw + ((size_t)k * DI_ + d) * R_;     // wave-uniform
    const float* al   = Alog + ((size_t)k * DI_ + d) * N_;    // wave-uniform
    float bias = dtb[k * DI_ + d];
    float Dv   = Dp[k * DI_ + d];

    const float* bc = xdbl + (size_t)(bb * K_ + k) * 64 * L;
    const float* ut = xmT + ((size_t)bb * DI_ + d) * L;
    float* yb = part + (size_t)(bb * K_ + k) * L * DI_ + d;

    int lj = lane < CW ? lane : CW - 1;
    int base = lj * SPL;

    float dl[SPL], du[SPL], uu[SPL], y[SPL];
    {
        float accv[SPL];
#pragma unroll
        for (int i = 0; i < SPL; i++) accv[i] = bias;
#pragma unroll 8
        for (int r = 0; r < R_; r++) {
            float wr = wrow[r];
            if constexpr (SPL == 4) {
                float4 d4 = *reinterpret_cast<const float4*>(bc + (size_t)r * L + base);
                accv[0] += d4.x * wr; accv[1] += d4.y * wr;
                accv[2] += d4.z * wr; accv[3] += d4.w * wr;
            } else {
                accv[0] += bc[(size_t)r * L + base] * wr;
            }
        }
#pragma unroll
        for (int i = 0; i < SPL; i++) {
            int src = dir_src(k, base + i, H, W, L);
            dl[i] = softplus_fast(accv[i]);
            uu[i] = ut[src];
            du[i] = dl[i] * uu[i];
            y[i] = 0.f;
        }
    }

#pragma unroll 1
    for (int n = 0; n < N_; n++) {
        float An = -__expf(al[n]);
        float aL, bL;
        if constexpr (SPL == 4) {
            float4 B4 = *reinterpret_cast<const float4*>(bc + (size_t)(R_ + n) * L + base);
            float a0 = __expf(dl[0] * An);
            float a1 = __expf(dl[1] * An);
            float a2 = __expf(dl[2] * An);
            float a3 = __expf(dl[3] * An);
            aL = a0; bL = du[0] * B4.x;
            bL = a1 * bL + du[1] * B4.y; aL = a1 * aL;
            bL = a2 * bL + du[2] * B4.z; aL = a2 * aL;
            bL = a3 * bL + du[3] * B4.w; aL = a3 * aL;
#pragma unroll
            for (int off = 1; off < CW; off <<= 1) {
                float ap = __shfl_up(aL, off);
                float bp = __shfl_up(bL, off);
                if (lane >= off) { bL = aL * bp + bL; aL = aL * ap; }
            }
            float hin = __shfl_up(bL, 1);
            if (lane == 0) hin = 0.f;
            float4 C4 = *reinterpret_cast<const float4*>(bc + (size_t)(R_ + N_ + n) * L + base);
            float h = hin;
            h = a0 * h + du[0] * B4.x; y[0] += h * C4.x;
            h = a1 * h + du[1] * B4.y; y[1] += h * C4.y;
            h = a2 * h + du[2] * B4.z; y[2] += h * C4.z;
            h = a3 * h + du[3] * B4.w; y[3] += h * C4.w;
        } else {
            float Bv = bc[(size_t)(R_ + n) * L + base];
            float a0 = __expf(dl[0] * An);
            aL = a0;
            bL = du[0] * Bv;
#pragma unroll
            for (int off = 1; off < CW; off <<= 1) {
                float ap = __shfl_up(aL, off);
                float bp = __shfl_up(bL, off);
                if (lane >= off) { bL = aL * bp + bL; aL = aL * ap; }
            }
            float hin = __shfl_up(bL, 1);
            if (lane == 0) hin = 0.f;
            float h = a0 * hin + du[0] * Bv;
            y[0] += h * bc[(size_t)(R_ + N_ + n) * L + base];
        }
    }

    if (lane < CW) {
#pragma unroll
        for (int i = 0; i < SPL; i++) {
            int src = dir_src(k, base + i, H, W, L);
            yb[(size_t)src * DI_] = y[i] + Dv * uu[i];
        }
    }
}

// --------------------------- fused merge4 + LN(y)*silu(z) ------------------
__global__ void k_merge_ln_silu(const float* __restrict__ part, const float* __restrict__ xz,
                                const float* __restrict__ onw, const float* __restrict__ onb,
                                float* __restrict__ tout, int L) {
    int row = blockIdx.x;            // b*L + l
    int bb = row / L, l = row % L;
    __shared__ float sd[256];
    __shared__ float srow[DI_];
    const float* p0 = part + ((size_t)(bb * K_ + 0) * L + l) * DI_;
    const float* p1 = part + ((size_t)(bb * K_ + 1) * L + l) * DI_;
    const float* p2 = part + ((size_t)(bb * K_ + 2) * L + l) * DI_;
    const float* p3 = part + ((size_t)(bb * K_ + 3) * L + l) * DI_;
    float sum = 0.f;
    for (int d = threadIdx.x; d < DI_; d += 256) {
        float v = p0[d] + p1[d] + p2[d] + p3[d];
        srow[d] = v; sum += v;
    }
    sum = blockReduceSum(sum, sd);
    float mu = sum / DI_;
    float vs = 0.f;
    for (int d = threadIdx.x; d < DI_; d += 256) { float dv = srow[d] - mu; vs += dv * dv; }
    vs = blockReduceSum(vs, sd);
    float rstd = rsqrtf(vs / DI_ + 1e-5f);
    const float* zp = xz + (size_t)row * 2 * DI_ + DI_;
    float* tp = tout + (size_t)row * DI_;
    for (int d = threadIdx.x; d < DI_; d += 256) {
        float zn = zp[d];
        tp[d] = ((srow[d] - mu) * rstd * onw[d] + onb[d]) * siluf(zn);
    }
}

// --------------------------- bilinear up + skip add ------------------------
__global__ void k_up_add(const float* __restrict__ low, const float* __restrict__ skip,
                         float* __restrict__ out, int Hi, int Wi, int Ho, int Wo) {
    int idx = blockIdx.x * 256 + threadIdx.x;            // (b,c,ho,wo)
    int total = B_ * C_ * Ho * Wo;
    if (idx >= total) return;
    int wo = idx % Wo; int t = idx / Wo; int ho = t % Ho; t /= Ho; int c = t % C_; int bb = t / C_;
    float fy = (float)ho * (float)(Hi - 1) / (float)(Ho - 1);
    float fx = (float)wo * (float)(Wi - 1) / (float)(Wo - 1);
    int y0 = (int)floorf(fy); int y1 = min(y0 + 1, Hi - 1); float wy = fy - (float)y0;
    int x0 = (int)floorf(fx); int x1 = min(x0 + 1, Wi - 1); float wx = fx - (float)x0;
    const float* lp = low + ((size_t)bb * C_ + c) * Hi * Wi;
    float g0 = lp[y0 * Wi + x0] * (1.f - wy) + lp[y1 * Wi + x0] * wy;
    float g1 = lp[y0 * Wi + x1] * (1.f - wy) + lp[y1 * Wi + x1] * wy;
    out[idx] = skip[idx] + g0 * (1.f - wx) + g1 * wx;
}

// --------------------------- diagnostic fill (f32) -------------------------
__global__ void k_fill_out(float* o, int n, float v) {
    int i = blockIdx.x * 256 + threadIdx.x;
    if (i < n) o[i] = v;
}

// ===========================================================================
struct VssW {
    const float *lnw, *lnb, *inproj, *convw, *convb, *xproj, *dtw, *dtb, *Alog, *D, *onw, *onb, *outproj;
};

static void run_vss(const float* xc_in, float* xc_out, const VssW& p, int H, int W,
                    float* xln, float* xz, float* xm, float* xmT, float* xdbl,
                    float* part, float* ybuf, float* tbuf, float* cpart2,
                    hipStream_t stream) {
    int L = H * W, M = B_ * L;
    k_ln_nchw<<<M, 256, 0, stream>>>(xc_in, p.lnw, p.lnb, xln, L, 1e-6f);
    {
        dim3 g(2 * DI_ / 64, M / 64);
        k_gemm_mfma<0><<<g, 256, 0, stream>>>(xln, p.inproj, xz, M, 2 * DI_, C_, nullptr, L);
    }
    {
        int tot = B_ * L * DI_;
        k_dwconv_silu<<<(tot + 255) / 256, 256, 0, stream>>>(xz, p.convw, p.convb, xm, xmT, H, W);
    }
    // ---- x_dbl = gather( sum_s partial(xproj_slab @ xm^T) ) : split-K x4 ----
    {
        float* tmp = ybuf;               // KSPL*256*M floats; <= 1048576 = ybuf size
        dim3 g(M / 64, (K_ * 64) / 64, KSPL);
        k_gemm_part<<<g, 256, 0, stream>>>(p.xproj, xm, tmp, K_ * 64, M, DI_);
        int tot = B_ * K_ * 64 * L;
        k_gather_xdbl<<<(tot + 255) / 256, 256, 0, stream>>>(tmp, xdbl, H, W);
    }
    {
        int g = B_ * K_ * (DI_ / 4);
        if (L == 256)
            k_scan_wave<256><<<g, 256, 0, stream>>>(xmT, xdbl, p.dtw, p.dtb, p.Alog, p.D, part, H, W);
        else if (L == 64)
            k_scan_wave<64><<<g, 256, 0, stream>>>(xmT, xdbl, p.dtw, p.dtb, p.Alog, p.D, part, H, W);
        else
            k_scan_wave<16><<<g, 256, 0, stream>>>(xmT, xdbl, p.dtw, p.dtb, p.Alog, p.D, part, H, W);
    }
    k_merge_ln_silu<<<M, 256, 0, stream>>>(part, xz, p.onw, p.onb, tbuf, L);
    // ---- outproj: split-K x4, fin adds residual (NCHW) ----
    {
        dim3 g(C_ / 64, M / 64, KSPL);
        k_gemm_part<<<g, 256, 0, stream>>>(tbuf, p.outproj, cpart2, M, C_, DI_);
        int tot = M * C_;
        k_outproj_fin<<<(tot + 255) / 256, 256, 0, stream>>>(cpart2, xc_in, xc_out, L);
    }
}

extern "C" void kernel_launch(void* const* d_in, const int* in_sizes, int n_in,
                              void* d_out, int out_size, void* d_ws, size_t ws_size,
                              hipStream_t stream) {
    constexpr size_t NEED_FLOATS = 14221312;
    constexpr size_t NEED_BYTES  = NEED_FLOATS * 4;   // 56,885,248
    if (ws_size < NEED_BYTES) {
        k_fill_out<<<(out_size + 255) / 256, 256, 0, stream>>>((float*)d_out, out_size, 0.0f);
        return;
    }

    const float* x        = (const float*)d_in[0];
    const float* lnw      = (const float*)d_in[1];
    const float* lnb      = (const float*)d_in[2];
    const float* inproj   = (const float*)d_in[3];
    const float* convw    = (const float*)d_in[4];
    const float* convb    = (const float*)d_in[5];
    const float* xprojp   = (const float*)d_in[6];
    const float* dtwp     = (const float*)d_in[7];
    const float* dtbp     = (const float*)d_in[8];
    const float* Alogp    = (const float*)d_in[9];
    const float* Dpp      = (const float*)d_in[10];
    const float* onwp     = (const float*)d_in[11];
    const float* onbp     = (const float*)d_in[12];
    const float* outprojp = (const float*)d_in[13];
    const float* ds_dw    = (const float*)d_in[14];
    const float* ds_bn1s  = (const float*)d_in[15];
    const float* ds_bn1b  = (const float*)d_in[16];
    const float* ds_pw    = (const float*)d_in[17];
    const float* ds_bn2s  = (const float*)d_in[18];
    const float* ds_bn2b  = (const float*)d_in[19];
    const float* fus_c1   = (const float*)d_in[20];
    const float* fus_bn1s = (const float*)d_in[21];
    const float* fus_bn1b = (const float*)d_in[22];
    const float* fus_c2   = (const float*)d_in[23];
    const float* fus_bn2s = (const float*)d_in[24];
    const float* fus_bn2b = (const float*)d_in[25];
    const float* op_bn0s  = (const float*)d_in[26];
    const float* op_bn0b  = (const float*)d_in[27];
    const float* op_conv  = (const float*)d_in[28];
    const float* op_bn1s  = (const float*)d_in[29];
    const float* op_bn1b  = (const float*)d_in[30];

    float* ws = (float*)d_ws;
    float* xln   = ws;                    // 524288
    float* xz    = ws + 524288;           // 2097152
    float* xm    = ws + 2621440;          // 1048576
    float* xdbl  = ws + 3670016;          // 262144
    float* ybuf  = ws + 3932160;          // 1048576 (xdbl split-K partials)
    float* part  = ws + 4980736;          // 4194304
    float* tbuf  = part;                  // reassigned below
    float* t_a   = ws + 9175040;          // 524288
    float* xr    = ws + 9699328;          // 524288
    float* p1    = ws + 10223616;         // 131072
    float* p2    = ws + 10354688;         // 32768
    float* proc0 = ws + 10387456;         // 524288
    float* proc1 = ws + 10911744;         // 131072
    float* proc2 = ws + 11042816;         // 32768
    float* xmT   = ws + 11075584;         // 1048576 (transposed xm)
    float* cpart2= ws + 12124160;         // 2097152 (split-K partials: conv/outproj/pw)
    // tbuf must NOT alias part (merge_ln_silu reads part while writing tbuf);
    // ybuf is dead by then (xdbl partials consumed by gather).
    tbuf = ybuf;
    float* p1preT= xz;                    // 131072 ((pixel, c) layout)
    float* p2preT= xz + 131072;           // 32768
    float* up1t  = xln;                   // 131072
    float* rbh1  = xln + 131072;          // 131072
    float* fus1  = xln + 262144;          // 131072
    float* up0t  = xm;                    // 524288
    float* rbh0  = part;                  // 524288
    float* hbuf  = part + 1048576;        // 524288
    short* icol = (short*)(ws + 6553600); // bf16 im2col, dead during VSS

    VssW vp[5];
    for (int i = 0; i < 5; i++) {
        vp[i].lnw     = lnw + (size_t)i * C_;
        vp[i].lnb     = lnb + (size_t)i * C_;
        vp[i].inproj  = inproj + (size_t)i * 2 * DI_ * C_;
        vp[i].convw   = convw + (size_t)i * DI_ * 9;
        vp[i].convb   = convb + (size_t)i * DI_;
        vp[i].xproj   = xprojp + (size_t)i * K_ * 64 * DI_;
        vp[i].dtw     = dtwp + (size_t)i * K_ * DI_ * R_;
        vp[i].dtb     = dtbp + (size_t)i * K_ * DI_;
        vp[i].Alog    = Alogp + (size_t)i * K_ * DI_ * N_;
        vp[i].D       = Dpp + (size_t)i * K_ * DI_;
        vp[i].onw     = onwp + (size_t)i * DI_;
        vp[i].onb     = onbp + (size_t)i * DI_;
        vp[i].outproj = outprojp + (size_t)i * C_ * DI_;
    }

    // ---- stem: two VSS at 16x16 ----
    run_vss(x,   t_a, vp[0], 16, 16, xln, xz, xm, xmT, xdbl, part, ybuf, tbuf, cpart2, stream);
    run_vss(t_a, xr,  vp[1], 16, 16, xln, xz, xm, xmT, xdbl, part, ybuf, tbuf, cpart2, stream);

    // ---- down 0: 16 -> 8 (dwconv -> (pixel,c); pwconv as split-K GEMM) ----
    k_dwconv_s2_bn_gelu<<<(B_ * C_ * 64 + 255) / 256, 256, 0, stream>>>(
        xr, ds_dw, ds_bn1s, ds_bn1b, p1preT, 16, 16);
    {
        int M = B_ * 64;                 // 256 pixels
        dim3 g(C_ / 64, M / 64, KSPL);
        k_gemm_part<<<g, 256, 0, stream>>>(p1preT, ds_pw, cpart2, M, C_, C_);
        k_pw_fin<<<(M * C_ + 255) / 256, 256, 0, stream>>>(cpart2, ds_bn2s, ds_bn2b, p1, M, 64);
    }
    // ---- down 1: 8 -> 4 ----
    k_dwconv_s2_bn_gelu<<<(B_ * C_ * 16 + 255) / 256, 256, 0, stream>>>(
        p1, ds_dw + (size_t)C_ * 9, ds_bn1s + C_, ds_bn1b + C_, p2preT, 8, 8);
    {
        int M = B_ * 16;                 // 64 pixels
        dim3 g(C_ / 64, M / 64, KSPL);
        k_gemm_part<<<g, 256, 0, stream>>>(p2preT, ds_pw + (size_t)C_ * C_, cpart2, M, C_, C_);
        k_pw_fin<<<(M * C_ + 255) / 256, 256, 0, stream>>>(cpart2, ds_bn2s + C_, ds_bn2b + C_, p2, M, 16);
    }

    // ---- per-scale VSS ----
    run_vss(xr, proc0, vp[2], 16, 16, xln, xz, xm, xmT, xdbl, part, ybuf, tbuf, cpart2, stream);
    run_vss(p1, proc1, vp[3],  8,  8, xln, xz, xm, xmT, xdbl, part, ybuf, tbuf, cpart2, stream);
    run_vss(p2, proc2, vp[4],  4,  4, xln, xz, xm, xmT, xdbl, part, ybuf, tbuf, cpart2, stream);

    // ---- fuse i=1: up(proc2: 4->8) + proc1, resblk j=0 (8x8, N=256) ----
    k_up_add<<<(B_ * C_ * 64 + 255) / 256, 256, 0, stream>>>(proc2, proc1, up1t, 4, 4, 8, 8);
    {
        int Nn = B_ * 64;
        int tot = Nn * (KC9 / 8);
        int tfin = C_ * Nn;
        dim3 gg(Nn / 64, C_ / 64, KSPL);
        k_im2col<<<(tot + 255) / 256, 256, 0, stream>>>(up1t, icol, 8, 8);
        k_gemm_conv_part<<<gg, 256, 0, stream>>>(fus_c1, icol, cpart2, Nn);
        k_conv_fin2<0><<<(tfin + 255) / 256, 256, 0, stream>>>(cpart2, fus_bn1s, fus_bn1b,
                                                               nullptr, rbh1, Nn, 64,
                                                               nullptr, nullptr);
        k_im2col<<<(tot + 255) / 256, 256, 0, stream>>>(rbh1, icol, 8, 8);
        k_gemm_conv_part<<<gg, 256, 0, stream>>>(fus_c2, icol, cpart2, Nn);
        k_conv_fin2<1><<<(tfin + 255) / 256, 256, 0, stream>>>(cpart2, fus_bn2s, fus_bn2b,
                                                               up1t, fus1, Nn, 64,
                                                               nullptr, nullptr);
    }
    // ---- fuse i=0: up(fus1: 8->16) + proc0, resblk j=1 (16x16, N=1024) ----
    // Second fin uses CM3: resblk epilogue + head bn0+gelu fused -> hbuf.
    k_up_add<<<(B_ * C_ * 256 + 255) / 256, 256, 0, stream>>>(fus1, proc0, up0t, 8, 8, 16, 16);
    {
        int Nn = B_ * 256;
        int tot = Nn * (KC9 / 8);
        int tfin = C_ * Nn;
        dim3 gg(Nn / 64, C_ / 64, KSPL);
        k_im2col<<<(tot + 255) / 256, 256, 0, stream>>>(up0t, icol, 16, 16);
        k_gemm_conv_part<<<gg, 256, 0, stream>>>(fus_c1 + (size_t)C_ * KC9, icol, cpart2, Nn);
        k_conv_fin2<0><<<(tfin + 255) / 256, 256, 0, stream>>>(cpart2, fus_bn1s + C_, fus_bn1b + C_,
                                                               nullptr, rbh0, Nn, 256,
                                                               nullptr, nullptr);
        k_im2col<<<(tot + 255) / 256, 256, 0, stream>>>(rbh0, icol, 16, 16);
        k_gemm_conv_part<<<gg, 256, 0, stream>>>(fus_c2 + (size_t)C_ * KC9, icol, cpart2, Nn);
        k_conv_fin2<3><<<(tfin + 255) / 256, 256, 0, stream>>>(cpart2, fus_bn2s + C_, fus_bn2b + C_,
                                                               up0t, hbuf, Nn, 256,
                                                               op_bn0s, op_bn0b);
    }

    // ---- output head (bn0+gelu already fused into CM3 above) ----
    {
        int Nn = B_ * 256;
        int tot = Nn * (KC9 / 8);
        int tfin = C_ * Nn;
        dim3 gg(Nn / 64, C_ / 64, KSPL);
        k_im2col<<<(tot + 255) / 256, 256, 0, stream>>>(hbuf, icol, 16, 16);
        k_gemm_conv_part<<<gg, 256, 0, stream>>>(op_conv, icol, cpart2, Nn);
        k_conv_fin2<2><<<(tfin + 255) / 256, 256, 0, stream>>>(cpart2, op_bn1s, op_bn1b,
                                                               x, (float*)d_out, Nn, 256,
                                                               nullptr, nullptr);
    }
    (void)in_sizes; (void)n_in; (void)out_size;
}

// Round 33
// 775.716 us; speedup vs baseline: 1.0383x; 1.0383x over previous
//
#include <hip/hip_runtime.h>
#include <hip/hip_bf16.h>
#include <math.h>

// ---------------------------------------------------------------------------
// HMABottleneck: B=4, C=512, H=W=16, DI=1024, K=4 dirs, N=16 states, R=32
// Round 33: REVERT to r31 (776 us). r32's x8-im2col regressed (-3.7%): 8
// serial dependent scattered loads/thread lost to the TLP of the 1-elem/thread
// form. This file is byte-identical to r31's kernel.
// ---------------------------------------------------------------------------

constexpr int B_  = 4;
constexpr int C_  = 512;
constexpr int DI_ = 1024;
constexpr int K_  = 4;
constexpr int N_  = 16;
constexpr int R_  = 32;
constexpr int KC9 = C_ * 9;                   // conv GEMM K dim = 4608
constexpr int KSPL = 4;                       // split-K factor (all split GEMMs)
constexpr int KSEG = KC9 / KSPL;              // 1152
constexpr float BNS_ = 0.9999950000374997f;   // 1/sqrt(1+1e-5)

typedef __attribute__((ext_vector_type(8))) short bf16x8;
typedef __attribute__((ext_vector_type(4))) float f32x4;

__device__ inline float geluf(float x) {
    return 0.5f * x * (1.0f + erff(x * 0.70710678118654752f));
}
__device__ inline float siluf(float x) {
    return x / (1.0f + expf(-x));
}
__device__ inline float softplusf(float x) {
    return fmaxf(x, 0.0f) + log1pf(expf(-fabsf(x)));
}
// fast variants: scan kernel only (args bounded, abs budget has 3x headroom)
__device__ inline float softplus_fast(float x) {
    return fmaxf(x, 0.0f) + __logf(1.0f + __expf(-fabsf(x)));
}
__device__ inline short bf16s(float x) {
    __hip_bfloat16 h = __float2bfloat16(x);
    return *reinterpret_cast<short*>(&h);
}

__device__ inline float blockReduceSum(float v, float* sd) {
    int tid = threadIdx.x;
    sd[tid] = v; __syncthreads();
    for (int s = blockDim.x / 2; s > 0; s >>= 1) {
        if (tid < s) sd[tid] += sd[tid + s];
        __syncthreads();
    }
    float r = sd[0]; __syncthreads();
    return r;
}

// --------------------------- LN over channels (NCHW -> (B*L, C)) -----------
__global__ void k_ln_nchw(const float* __restrict__ x, const float* __restrict__ w,
                          const float* __restrict__ b, float* __restrict__ out,
                          int L, float eps) {
    int row = blockIdx.x;            // b*L + l
    int bb = row / L, l = row % L;
    __shared__ float sd[256];
    __shared__ float srow[C_];
    const float* xp = x + (size_t)bb * C_ * L + l;
    float sum = 0.f;
    for (int c = threadIdx.x; c < C_; c += 256) { float v = xp[(size_t)c * L]; srow[c] = v; sum += v; }
    sum = blockReduceSum(sum, sd);
    float mu = sum / C_;
    float vs = 0.f;
    for (int c = threadIdx.x; c < C_; c += 256) { float d = srow[c] - mu; vs += d * d; }
    vs = blockReduceSum(vs, sd);
    float rstd = rsqrtf(vs / C_ + eps);
    float* op = out + (size_t)row * C_;
    for (int c = threadIdx.x; c < C_; c += 256) op[c] = (srow[c] - mu) * rstd * w[c] + b[c];
}

// --------------------------- bf16 MFMA GEMM: out = A (M,K) * Bw(N,K)^T -----
template <int EPI>
__global__ void k_gemm_mfma(const float* __restrict__ A, const float* __restrict__ Bw,
                            float* __restrict__ Cout, int M, int Nn, int Kk,
                            const float* __restrict__ Res, int L) {
    const int BK = 32, PITCH = 40;
    __shared__ short As[64 * PITCH];
    __shared__ short Bs[64 * PITCH];
    int m0 = blockIdx.y * 64, n0 = blockIdx.x * 64;
    int tid = threadIdx.x;
    int wv = tid >> 6, lane = tid & 63;
    int frow = lane & 15, kg = lane >> 4;
    f32x4 acc[4];
#pragma unroll
    for (int t = 0; t < 4; t++) acc[t] = (f32x4){0.f, 0.f, 0.f, 0.f};

    int sr = tid >> 2;
    int kq = (tid & 3) * 4;
    for (int k0 = 0; k0 < Kk; k0 += BK) {
        const float* ap = A + (size_t)(m0 + sr) * Kk + k0;
        const float* bp = Bw + (size_t)(n0 + sr) * Kk + k0;
        float4 a1 = *reinterpret_cast<const float4*>(ap + kq);
        float4 a2 = *reinterpret_cast<const float4*>(ap + kq + 16);
        float4 b1 = *reinterpret_cast<const float4*>(bp + kq);
        float4 b2 = *reinterpret_cast<const float4*>(bp + kq + 16);
        short* ad = &As[sr * PITCH + kq];
        ad[0] = bf16s(a1.x); ad[1] = bf16s(a1.y); ad[2] = bf16s(a1.z); ad[3] = bf16s(a1.w);
        ad[16] = bf16s(a2.x); ad[17] = bf16s(a2.y); ad[18] = bf16s(a2.z); ad[19] = bf16s(a2.w);
        short* bd = &Bs[sr * PITCH + kq];
        bd[0] = bf16s(b1.x); bd[1] = bf16s(b1.y); bd[2] = bf16s(b1.z); bd[3] = bf16s(b1.w);
        bd[16] = bf16s(b2.x); bd[17] = bf16s(b2.y); bd[18] = bf16s(b2.z); bd[19] = bf16s(b2.w);
        __syncthreads();
        bf16x8 afrag = *reinterpret_cast<const bf16x8*>(&As[(wv * 16 + frow) * PITCH + kg * 8]);
#pragma unroll
        for (int t = 0; t < 4; t++) {
            bf16x8 bfrag = *reinterpret_cast<const bf16x8*>(&Bs[(t * 16 + frow) * PITCH + kg * 8]);
            acc[t] = __builtin_amdgcn_mfma_f32_16x16x32_bf16(afrag, bfrag, acc[t], 0, 0, 0);
        }
        __syncthreads();
    }

    int orow = kg * 4;
#pragma unroll
    for (int t = 0; t < 4; t++) {
#pragma unroll
        for (int r = 0; r < 4; r++) {
            int m = m0 + wv * 16 + orow + r;
            int n = n0 + t * 16 + frow;
            if (EPI == 0) {
                Cout[(size_t)m * Nn + n] = acc[t][r];
            } else {
                int bb = m / L, l = m % L;
                size_t o = ((size_t)bb * C_ + n) * L + l;
                Cout[o] = Res[o] + acc[t][r];
            }
        }
    }
}

// --------------------------- split-K partial GEMM (f32 inputs) -------------
__global__ void k_gemm_part(const float* __restrict__ A, const float* __restrict__ Bw,
                            float* __restrict__ partial, int M, int Nn, int Kk) {
    const int BK = 32, PITCH = 40;
    __shared__ short As[64 * PITCH];
    __shared__ short Bs[64 * PITCH];
    int m0 = blockIdx.y * 64, n0 = blockIdx.x * 64;
    int s = blockIdx.z;
    int tid = threadIdx.x;
    int wv = tid >> 6, lane = tid & 63;
    int frow = lane & 15, kg = lane >> 4;
    f32x4 acc[4];
#pragma unroll
    for (int t = 0; t < 4; t++) acc[t] = (f32x4){0.f, 0.f, 0.f, 0.f};

    int sr = tid >> 2;
    int kq = (tid & 3) * 4;
    int kseg = Kk / KSPL;
    int kbeg = s * kseg;
    for (int k0 = kbeg; k0 < kbeg + kseg; k0 += BK) {
        const float* ap = A + (size_t)(m0 + sr) * Kk + k0;
        const float* bp = Bw + (size_t)(n0 + sr) * Kk + k0;
        float4 a1 = *reinterpret_cast<const float4*>(ap + kq);
        float4 a2 = *reinterpret_cast<const float4*>(ap + kq + 16);
        float4 b1 = *reinterpret_cast<const float4*>(bp + kq);
        float4 b2 = *reinterpret_cast<const float4*>(bp + kq + 16);
        short* ad = &As[sr * PITCH + kq];
        ad[0] = bf16s(a1.x); ad[1] = bf16s(a1.y); ad[2] = bf16s(a1.z); ad[3] = bf16s(a1.w);
        ad[16] = bf16s(a2.x); ad[17] = bf16s(a2.y); ad[18] = bf16s(a2.z); ad[19] = bf16s(a2.w);
        short* bd = &Bs[sr * PITCH + kq];
        bd[0] = bf16s(b1.x); bd[1] = bf16s(b1.y); bd[2] = bf16s(b1.z); bd[3] = bf16s(b1.w);
        bd[16] = bf16s(b2.x); bd[17] = bf16s(b2.y); bd[18] = bf16s(b2.z); bd[19] = bf16s(b2.w);
        __syncthreads();
        bf16x8 afrag = *reinterpret_cast<const bf16x8*>(&As[(wv * 16 + frow) * PITCH + kg * 8]);
#pragma unroll
        for (int t = 0; t < 4; t++) {
            bf16x8 bfrag = *reinterpret_cast<const bf16x8*>(&Bs[(t * 16 + frow) * PITCH + kg * 8]);
            acc[t] = __builtin_amdgcn_mfma_f32_16x16x32_bf16(afrag, bfrag, acc[t], 0, 0, 0);
        }
        __syncthreads();
    }

    int orow = kg * 4;
    float* pb = partial + (size_t)s * M * Nn;
#pragma unroll
    for (int t = 0; t < 4; t++) {
#pragma unroll
        for (int r = 0; r < 4; r++) {
            int m = m0 + wv * 16 + orow + r;
            int n = n0 + t * 16 + frow;
            pb[(size_t)m * Nn + n] = acc[t][r];
        }
    }
}

// --------------------------- outproj fin: sum partials + residual ----------
__global__ void k_outproj_fin(const float* __restrict__ partial, const float* __restrict__ res,
                              float* __restrict__ out, int L) {
    int Nn = C_;
    int total = B_ * L * Nn;
    int idx = blockIdx.x * 256 + threadIdx.x;
    if (idx >= total) return;
    int m = idx / Nn, n = idx % Nn;
    float a = 0.f;
#pragma unroll
    for (int s = 0; s < KSPL; s++) a += partial[(size_t)s * B_ * L * Nn + idx];
    int bb = m / L, l = m % L;
    size_t o = ((size_t)bb * C_ + n) * L + l;
    out[o] = res[o] + a;
}

// --------------------------- pw fin: sum partials + BN + GELU -> NCHW ------
__global__ void k_pw_fin(const float* __restrict__ partial, const float* __restrict__ bns,
                         const float* __restrict__ bnb, float* __restrict__ out,
                         int M, int L2) {
    int total = M * C_;
    int idx = blockIdx.x * 256 + threadIdx.x;
    if (idx >= total) return;
    int m = idx / C_, n = idx % C_;
    float a = 0.f;
#pragma unroll
    for (int s = 0; s < KSPL; s++) a += partial[(size_t)s * M * C_ + idx];
    int bb = m / L2, l = m % L2;
    out[((size_t)bb * C_ + n) * L2 + l] = geluf(a * (bns[n] * BNS_) + bnb[n]);
}

// --------------------------- im2col (bf16): icol[n][ci*9+q] ----------------
__global__ void k_im2col(const float* __restrict__ inp, short* __restrict__ ocol,
                         int H, int W) {
    int L = H * W;
    int total = B_ * L * KC9;
    int idx = blockIdx.x * 256 + threadIdx.x;
    if (idx >= total) return;
    int kidx = idx % KC9; int n = idx / KC9;
    int ci = kidx / 9; int q = kidx % 9;
    int dy = q / 3, dx = q % 3;
    int l = n % L; int bb = n / L;
    int h = l / W, w = l % W;
    int hh = h + dy - 1, ww = w + dx - 1;
    float v = 0.f;
    if ((unsigned)hh < (unsigned)H && (unsigned)ww < (unsigned)W)
        v = inp[(((size_t)bb * C_ + ci) * H + hh) * W + ww];
    ocol[idx] = bf16s(v);
}

// --------------------------- conv GEMM split-K partial ---------------------
__global__ void k_gemm_conv_part(const float* __restrict__ wgt, const short* __restrict__ bcol,
                                 float* __restrict__ partial, int Nn) {
    const int BK = 32, PITCH = 40;
    __shared__ short As[64 * PITCH];
    __shared__ short Bs[64 * PITCH];
    int m0 = blockIdx.y * 64, n0 = blockIdx.x * 64;
    int s = blockIdx.z;
    int tid = threadIdx.x;
    int wv = tid >> 6, lane = tid & 63;
    int frow = lane & 15, kg = lane >> 4;
    f32x4 acc[4];
#pragma unroll
    for (int t = 0; t < 4; t++) acc[t] = (f32x4){0.f, 0.f, 0.f, 0.f};

    int sr = tid >> 2;
    int kq = (tid & 3) * 4;
    int kq8 = (tid & 3) * 8;
    int kbeg = s * KSEG;
    for (int k0 = kbeg; k0 < kbeg + KSEG; k0 += BK) {
        const float* ap = wgt + (size_t)(m0 + sr) * KC9 + k0;
        float4 a1 = *reinterpret_cast<const float4*>(ap + kq);
        float4 a2 = *reinterpret_cast<const float4*>(ap + kq + 16);
        short* ad = &As[sr * PITCH + kq];
        ad[0] = bf16s(a1.x); ad[1] = bf16s(a1.y); ad[2] = bf16s(a1.z); ad[3] = bf16s(a1.w);
        ad[16] = bf16s(a2.x); ad[17] = bf16s(a2.y); ad[18] = bf16s(a2.z); ad[19] = bf16s(a2.w);
        uint4 bv = *reinterpret_cast<const uint4*>(bcol + (size_t)(n0 + sr) * KC9 + k0 + kq8);
        *reinterpret_cast<uint4*>(&Bs[sr * PITCH + kq8]) = bv;
        __syncthreads();
        bf16x8 afrag = *reinterpret_cast<const bf16x8*>(&As[(wv * 16 + frow) * PITCH + kg * 8]);
#pragma unroll
        for (int t = 0; t < 4; t++) {
            bf16x8 bfrag = *reinterpret_cast<const bf16x8*>(&Bs[(t * 16 + frow) * PITCH + kg * 8]);
            acc[t] = __builtin_amdgcn_mfma_f32_16x16x32_bf16(afrag, bfrag, acc[t], 0, 0, 0);
        }
        __syncthreads();
    }

    int orow = kg * 4;
    float* pb = partial + (size_t)s * C_ * Nn;
#pragma unroll
    for (int t = 0; t < 4; t++) {
#pragma unroll
        for (int r = 0; r < 4; r++) {
            int m = m0 + wv * 16 + orow + r;
            int n = n0 + t * 16 + frow;
            pb[(size_t)m * Nn + n] = acc[t][r];
        }
    }
}

// --------------------------- conv fin: sum KSPL partials + epilogue --------
// CM 0: gelu(bn(a));  CM 1: gelu(bn(a)+res);  CM 2: gelu(bn(a))+res;
// CM 3: gelu(bn2(gelu(bn(a)+res)))   (resblk fin + head bn0+gelu fused)
template <int CM>
__global__ void k_conv_fin2(const float* __restrict__ partial, const float* __restrict__ bns,
                            const float* __restrict__ bnb, const float* __restrict__ res,
                            float* __restrict__ out, int Nn, int L,
                            const float* __restrict__ bns2, const float* __restrict__ bnb2) {
    int idx = blockIdx.x * 256 + threadIdx.x;    // (m, n) n fastest
    int total = C_ * Nn;
    if (idx >= total) return;
    int m = idx / Nn, n = idx % Nn;
    float a = 0.f;
#pragma unroll
    for (int s = 0; s < KSPL; s++) a += partial[(size_t)s * C_ * Nn + idx];
    int bb = n / L, l = n % L;
    size_t o = ((size_t)bb * C_ + m) * L + l;
    a = a * (bns[m] * BNS_) + bnb[m];
    if (CM == 0) out[o] = geluf(a);
    else if (CM == 1) out[o] = geluf(a + res[o]);
    else if (CM == 2) out[o] = geluf(a) + res[o];
    else {
        float v = geluf(a + res[o]);
        out[o] = geluf(v * (bns2[m] * BNS_) + bnb2[m]);
    }
}

// --------------------------- depthwise 3x3 s2 + BN + GELU -> (pixel, c) ----
__global__ void k_dwconv_s2_bn_gelu(const float* __restrict__ x, const float* __restrict__ dw,
                                    const float* __restrict__ bns, const float* __restrict__ bnb,
                                    float* __restrict__ out, int Hi, int Wi) {
    int Ho = Hi / 2, Wo = Wi / 2;
    int idx = blockIdx.x * 256 + threadIdx.x;            // (b,ho,wo,c) c fastest
    int total = B_ * C_ * Ho * Wo;
    if (idx >= total) return;
    int c = idx % C_; int t = idx / C_; int wo = t % Wo; t /= Wo; int ho = t % Ho; int bb = t / Ho;
    float acc = 0.f;
    const float* xp = x + ((size_t)bb * C_ + c) * Hi * Wi;
    const float* wp = dw + c * 9;
#pragma unroll
    for (int dy = 0; dy < 3; dy++) {
        int ih = ho * 2 + dy - 1;
        if ((unsigned)ih >= (unsigned)Hi) continue;
#pragma unroll
        for (int dx = 0; dx < 3; dx++) {
            int iw = wo * 2 + dx - 1;
            if ((unsigned)iw >= (unsigned)Wi) continue;
            acc += xp[ih * Wi + iw] * wp[dy * 3 + dx];
        }
    }
    acc = acc * (bns[c] * BNS_) + bnb[c];
    out[((size_t)(bb * Ho + ho) * Wo + wo) * C_ + c] = geluf(acc);
}

// --------------------------- depthwise 3x3 (pad1) + bias + SiLU ------------
__global__ void k_dwconv_silu(const float* __restrict__ xz, const float* __restrict__ cw,
                              const float* __restrict__ cb, float* __restrict__ xm,
                              float* __restrict__ xmT, int H, int W) {
    int L = H * W;
    int idx = blockIdx.x * 256 + threadIdx.x;            // (b, l, d) d fastest
    int total = B_ * L * DI_;
    if (idx >= total) return;
    int d = idx % DI_; int t = idx / DI_; int l = t % L; int bb = t / L;
    int h = l / W, w = l % W;
    float acc = cb[d];
    const float* wp = cw + d * 9;
#pragma unroll
    for (int dy = 0; dy < 3; dy++) {
        int hh = h + dy - 1;
        if ((unsigned)hh >= (unsigned)H) continue;
#pragma unroll
        for (int dx = 0; dx < 3; dx++) {
            int ww = w + dx - 1;
            if ((unsigned)ww >= (unsigned)W) continue;
            acc += xz[((size_t)bb * L + hh * W + ww) * (2 * DI_) + d] * wp[dy * 3 + dx];
        }
    }
    float v = siluf(acc);
    xm[idx] = v;
    xmT[((size_t)bb * DI_ + d) * L + l] = v;
}

// map (k,l) -> source flat index in row-major (h*W+w) order
__device__ inline int dir_src(int k, int l, int H, int W, int L) {
    int ll = (k >= 2) ? (L - 1 - l) : l;
    return (k & 1) ? ((ll % H) * W + ll / H) : ll;
}

// --------------------------- gather: xdbl from split-K partials ------------
__global__ void k_gather_xdbl(const float* __restrict__ tmp, float* __restrict__ xdbl,
                              int H, int W) {
    int L = H * W;
    int Nn = B_ * L;
    int total = B_ * K_ * 64 * L;
    int idx = blockIdx.x * 256 + threadIdx.x;
    if (idx >= total) return;
    int l = idx % L; int t = idx / L; int c = t % 64; t /= 64; int k = t % K_; int bb = t / K_;
    int src = dir_src(k, l, H, W, L);
    size_t col = (size_t)bb * L + src;
    float v = 0.f;
#pragma unroll
    for (int s = 0; s < KSPL; s++)
        v += tmp[((size_t)s * K_ * 64 + k * 64 + c) * Nn + col];
    xdbl[idx] = v;
}

// --------------------------- wave scan, SPL steps per lane (r28 form) ------
template <int LT>
__global__ void k_scan_wave(const float* __restrict__ xmT, const float* __restrict__ xdbl,
                            const float* __restrict__ dtw, const float* __restrict__ dtb,
                            const float* __restrict__ Alog, const float* __restrict__ Dp,
                            float* __restrict__ part, int H, int W) {
    constexpr int SPL = (LT == 256) ? 4 : 1;
    constexpr int CW  = (LT < 64) ? LT : 64;
    const int L = LT;
    int lane = threadIdx.x & 63;
    int wv = threadIdx.x >> 6;
    int blk = blockIdx.x;                // (bb, k, dq)
    const int ndq = DI_ / 4;
    int dq = blk % ndq; int t2 = blk / ndq; int k = t2 % K_; int bb = t2 / K_;
    int d = dq * 4 + wv;

    const float* wrow = dtw + ((size_t)k * DI_ + d) * R_;     // wave-uniform
    const float* al   = Alog + ((size_t)k * DI_ + d) * N_;    // wave-uniform
    float bias = dtb[k * DI_ + d];
    float Dv   = Dp[k * DI_ + d];

    const float* bc = xdbl + (size_t)(bb * K_ + k) * 64 * L;
    const float* ut = xmT + ((size_t)bb * DI_ + d) * L;
    float* yb = part + (size_t)(bb * K_ + k) * L * DI_ + d;

    int lj = lane < CW ? lane : CW - 1;
    int base = lj * SPL;

    float dl[SPL], du[SPL], uu[SPL], y[SPL];
    {
        float accv[SPL];
#pragma unroll
        for (int i = 0; i < SPL; i++) accv[i] = bias;
#pragma unroll 8
        for (int r = 0; r < R_; r++) {
            float wr = wrow[r];
            if constexpr (SPL == 4) {
                float4 d4 = *reinterpret_cast<const float4*>(bc + (size_t)r * L + base);
                accv[0] += d4.x * wr; accv[1] += d4.y * wr;
                accv[2] += d4.z * wr; accv[3] += d4.w * wr;
            } else {
                accv[0] += bc[(size_t)r * L + base] * wr;
            }
        }
#pragma unroll
        for (int i = 0; i < SPL; i++) {
            int src = dir_src(k, base + i, H, W, L);
            dl[i] = softplus_fast(accv[i]);
            uu[i] = ut[src];
            du[i] = dl[i] * uu[i];
            y[i] = 0.f;
        }
    }

#pragma unroll 1
    for (int n = 0; n < N_; n++) {
        float An = -__expf(al[n]);
        float aL, bL;
        if constexpr (SPL == 4) {
            float4 B4 = *reinterpret_cast<const float4*>(bc + (size_t)(R_ + n) * L + base);
            float a0 = __expf(dl[0] * An);
            float a1 = __expf(dl[1] * An);
            float a2 = __expf(dl[2] * An);
            float a3 = __expf(dl[3] * An);
            aL = a0; bL = du[0] * B4.x;
            bL = a1 * bL + du[1] * B4.y; aL = a1 * aL;
            bL = a2 * bL + du[2] * B4.z; aL = a2 * aL;
            bL = a3 * bL + du[3] * B4.w; aL = a3 * aL;
#pragma unroll
            for (int off = 1; off < CW; off <<= 1) {
                float ap = __shfl_up(aL, off);
                float bp = __shfl_up(bL, off);
                if (lane >= off) { bL = aL * bp + bL; aL = aL * ap; }
            }
            float hin = __shfl_up(bL, 1);
            if (lane == 0) hin = 0.f;
            float4 C4 = *reinterpret_cast<const float4*>(bc + (size_t)(R_ + N_ + n) * L + base);
            float h = hin;
            h = a0 * h + du[0] * B4.x; y[0] += h * C4.x;
            h = a1 * h + du[1] * B4.y; y[1] += h * C4.y;
            h = a2 * h + du[2] * B4.z; y[2] += h * C4.z;
            h = a3 * h + du[3] * B4.w; y[3] += h * C4.w;
        } else {
            float Bv = bc[(size_t)(R_ + n) * L + base];
            float a0 = __expf(dl[0] * An);
            aL = a0;
            bL = du[0] * Bv;
#pragma unroll
            for (int off = 1; off < CW; off <<= 1) {
                float ap = __shfl_up(aL, off);
                float bp = __shfl_up(bL, off);
                if (lane >= off) { bL = aL * bp + bL; aL = aL * ap; }
            }
            float hin = __shfl_up(bL, 1);
            if (lane == 0) hin = 0.f;
            float h = a0 * hin + du[0] * Bv;
            y[0] += h * bc[(size_t)(R_ + N_ + n) * L + base];
        }
    }

    if (lane < CW) {
#pragma unroll
        for (int i = 0; i < SPL; i++) {
            int src = dir_src(k, base + i, H, W, L);
            yb[(size_t)src * DI_] = y[i] + Dv * uu[i];
        }
    }
}

// --------------------------- fused merge4 + LN(y)*silu(z) ------------------
__global__ void k_merge_ln_silu(const float* __restrict__ part, const float* __restrict__ xz,
                                const float* __restrict__ onw, const float* __restrict__ onb,
                                float* __restrict__ tout, int L) {
    int row = blockIdx.x;            // b*L + l
    int bb = row / L, l = row % L;
    __shared__ float sd[256];
    __shared__ float srow[DI_];
    const float* p0 = part + ((size_t)(bb * K_ + 0) * L + l) * DI_;
    const float* p1 = part + ((size_t)(bb * K_ + 1) * L + l) * DI_;
    const float* p2 = part + ((size_t)(bb * K_ + 2) * L + l) * DI_;
    const float* p3 = part + ((size_t)(bb * K_ + 3) * L + l) * DI_;
    float sum = 0.f;
    for (int d = threadIdx.x; d < DI_; d += 256) {
        float v = p0[d] + p1[d] + p2[d] + p3[d];
        srow[d] = v; sum += v;
    }
    sum = blockReduceSum(sum, sd);
    float mu = sum / DI_;
    float vs = 0.f;
    for (int d = threadIdx.x; d < DI_; d += 256) { float dv = srow[d] - mu; vs += dv * dv; }
    vs = blockReduceSum(vs, sd);
    float rstd = rsqrtf(vs / DI_ + 1e-5f);
    const float* zp = xz + (size_t)row * 2 * DI_ + DI_;
    float* tp = tout + (size_t)row * DI_;
    for (int d = threadIdx.x; d < DI_; d += 256) {
        float zn = zp[d];
        tp[d] = ((srow[d] - mu) * rstd * onw[d] + onb[d]) * siluf(zn);
    }
}

// --------------------------- bilinear up + skip add ------------------------
__global__ void k_up_add(const float* __restrict__ low, const float* __restrict__ skip,
                         float* __restrict__ out, int Hi, int Wi, int Ho, int Wo) {
    int idx = blockIdx.x * 256 + threadIdx.x;            // (b,c,ho,wo)
    int total = B_ * C_ * Ho * Wo;
    if (idx >= total) return;
    int wo = idx % Wo; int t = idx / Wo; int ho = t % Ho; t /= Ho; int c = t % C_; int bb = t / C_;
    float fy = (float)ho * (float)(Hi - 1) / (float)(Ho - 1);
    float fx = (float)wo * (float)(Wi - 1) / (float)(Wo - 1);
    int y0 = (int)floorf(fy); int y1 = min(y0 + 1, Hi - 1); float wy = fy - (float)y0;
    int x0 = (int)floorf(fx); int x1 = min(x0 + 1, Wi - 1); float wx = fx - (float)x0;
    const float* lp = low + ((size_t)bb * C_ + c) * Hi * Wi;
    float g0 = lp[y0 * Wi + x0] * (1.f - wy) + lp[y1 * Wi + x0] * wy;
    float g1 = lp[y0 * Wi + x1] * (1.f - wy) + lp[y1 * Wi + x1] * wy;
    out[idx] = skip[idx] + g0 * (1.f - wx) + g1 * wx;
}

// --------------------------- diagnostic fill (f32) -------------------------
__global__ void k_fill_out(float* o, int n, float v) {
    int i = blockIdx.x * 256 + threadIdx.x;
    if (i < n) o[i] = v;
}

// ===========================================================================
struct VssW {
    const float *lnw, *lnb, *inproj, *convw, *convb, *xproj, *dtw, *dtb, *Alog, *D, *onw, *onb, *outproj;
};

static void run_vss(const float* xc_in, float* xc_out, const VssW& p, int H, int W,
                    float* xln, float* xz, float* xm, float* xmT, float* xdbl,
                    float* part, float* ybuf, float* tbuf, float* cpart2,
                    hipStream_t stream) {
    int L = H * W, M = B_ * L;
    k_ln_nchw<<<M, 256, 0, stream>>>(xc_in, p.lnw, p.lnb, xln, L, 1e-6f);
    {
        dim3 g(2 * DI_ / 64, M / 64);
        k_gemm_mfma<0><<<g, 256, 0, stream>>>(xln, p.inproj, xz, M, 2 * DI_, C_, nullptr, L);
    }
    {
        int tot = B_ * L * DI_;
        k_dwconv_silu<<<(tot + 255) / 256, 256, 0, stream>>>(xz, p.convw, p.convb, xm, xmT, H, W);
    }
    // ---- x_dbl = gather( sum_s partial(xproj_slab @ xm^T) ) : split-K x4 ----
    {
        float* tmp = ybuf;               // KSPL*256*M floats; <= 1048576 = ybuf size
        dim3 g(M / 64, (K_ * 64) / 64, KSPL);
        k_gemm_part<<<g, 256, 0, stream>>>(p.xproj, xm, tmp, K_ * 64, M, DI_);
        int tot = B_ * K_ * 64 * L;
        k_gather_xdbl<<<(tot + 255) / 256, 256, 0, stream>>>(tmp, xdbl, H, W);
    }
    {
        int g = B_ * K_ * (DI_ / 4);
        if (L == 256)
            k_scan_wave<256><<<g, 256, 0, stream>>>(xmT, xdbl, p.dtw, p.dtb, p.Alog, p.D, part, H, W);
        else if (L == 64)
            k_scan_wave<64><<<g, 256, 0, stream>>>(xmT, xdbl, p.dtw, p.dtb, p.Alog, p.D, part, H, W);
        else
            k_scan_wave<16><<<g, 256, 0, stream>>>(xmT, xdbl, p.dtw, p.dtb, p.Alog, p.D, part, H, W);
    }
    k_merge_ln_silu<<<M, 256, 0, stream>>>(part, xz, p.onw, p.onb, tbuf, L);
    // ---- outproj: split-K x4, fin adds residual (NCHW) ----
    {
        dim3 g(C_ / 64, M / 64, KSPL);
        k_gemm_part<<<g, 256, 0, stream>>>(tbuf, p.outproj, cpart2, M, C_, DI_);
        int tot = M * C_;
        k_outproj_fin<<<(tot + 255) / 256, 256, 0, stream>>>(cpart2, xc_in, xc_out, L);
    }
}

extern "C" void kernel_launch(void* const* d_in, const int* in_sizes, int n_in,
                              void* d_out, int out_size, void* d_ws, size_t ws_size,
                              hipStream_t stream) {
    constexpr size_t NEED_FLOATS = 14221312;
    constexpr size_t NEED_BYTES  = NEED_FLOATS * 4;   // 56,885,248
    if (ws_size < NEED_BYTES) {
        k_fill_out<<<(out_size + 255) / 256, 256, 0, stream>>>((float*)d_out, out_size, 0.0f);
        return;
    }

    const float* x        = (const float*)d_in[0];
    const float* lnw      = (const float*)d_in[1];
    const float* lnb      = (const float*)d_in[2];
    const float* inproj   = (const float*)d_in[3];
    const float* convw    = (const float*)d_in[4];
    const float* convb    = (const float*)d_in[5];
    const float* xprojp   = (const float*)d_in[6];
    const float* dtwp     = (const float*)d_in[7];
    const float* dtbp     = (const float*)d_in[8];
    const float* Alogp    = (const float*)d_in[9];
    const float* Dpp      = (const float*)d_in[10];
    const float* onwp     = (const float*)d_in[11];
    const float* onbp     = (const float*)d_in[12];
    const float* outprojp = (const float*)d_in[13];
    const float* ds_dw    = (const float*)d_in[14];
    const float* ds_bn1s  = (const float*)d_in[15];
    const float* ds_bn1b  = (const float*)d_in[16];
    const float* ds_pw    = (const float*)d_in[17];
    const float* ds_bn2s  = (const float*)d_in[18];
    const float* ds_bn2b  = (const float*)d_in[19];
    const float* fus_c1   = (const float*)d_in[20];
    const float* fus_bn1s = (const float*)d_in[21];
    const float* fus_bn1b = (const float*)d_in[22];
    const float* fus_c2   = (const float*)d_in[23];
    const float* fus_bn2s = (const float*)d_in[24];
    const float* fus_bn2b = (const float*)d_in[25];
    const float* op_bn0s  = (const float*)d_in[26];
    const float* op_bn0b  = (const float*)d_in[27];
    const float* op_conv  = (const float*)d_in[28];
    const float* op_bn1s  = (const float*)d_in[29];
    const float* op_bn1b  = (const float*)d_in[30];

    float* ws = (float*)d_ws;
    float* xln   = ws;                    // 524288
    float* xz    = ws + 524288;           // 2097152
    float* xm    = ws + 2621440;          // 1048576
    float* xdbl  = ws + 3670016;          // 262144
    float* ybuf  = ws + 3932160;          // 1048576 (xdbl split-K partials)
    float* part  = ws + 4980736;          // 4194304
    float* tbuf  = part;                  // reassigned below
    float* t_a   = ws + 9175040;          // 524288
    float* xr    = ws + 9699328;          // 524288
    float* p1    = ws + 10223616;         // 131072
    float* p2    = ws + 10354688;         // 32768
    float* proc0 = ws + 10387456;         // 524288
    float* proc1 = ws + 10911744;         // 131072
    float* proc2 = ws + 11042816;         // 32768
    float* xmT   = ws + 11075584;         // 1048576 (transposed xm)
    float* cpart2= ws + 12124160;         // 2097152 (split-K partials: conv/outproj/pw)
    // tbuf must NOT alias part (merge_ln_silu reads part while writing tbuf);
    // ybuf is dead by then (xdbl partials consumed by gather).
    tbuf = ybuf;
    float* p1preT= xz;                    // 131072 ((pixel, c) layout)
    float* p2preT= xz + 131072;           // 32768
    float* up1t  = xln;                   // 131072
    float* rbh1  = xln + 131072;          // 131072
    float* fus1  = xln + 262144;          // 131072
    float* up0t  = xm;                    // 524288
    float* rbh0  = part;                  // 524288
    float* hbuf  = part + 1048576;        // 524288
    short* icol = (short*)(ws + 6553600); // bf16 im2col, dead during VSS

    VssW vp[5];
    for (int i = 0; i < 5; i++) {
        vp[i].lnw     = lnw + (size_t)i * C_;
        vp[i].lnb     = lnb + (size_t)i * C_;
        vp[i].inproj  = inproj + (size_t)i * 2 * DI_ * C_;
        vp[i].convw   = convw + (size_t)i * DI_ * 9;
        vp[i].convb   = convb + (size_t)i * DI_;
        vp[i].xproj   = xprojp + (size_t)i * K_ * 64 * DI_;
        vp[i].dtw     = dtwp + (size_t)i * K_ * DI_ * R_;
        vp[i].dtb     = dtbp + (size_t)i * K_ * DI_;
        vp[i].Alog    = Alogp + (size_t)i * K_ * DI_ * N_;
        vp[i].D       = Dpp + (size_t)i * K_ * DI_;
        vp[i].onw     = onwp + (size_t)i * DI_;
        vp[i].onb     = onbp + (size_t)i * DI_;
        vp[i].outproj = outprojp + (size_t)i * C_ * DI_;
    }

    // ---- stem: two VSS at 16x16 ----
    run_vss(x,   t_a, vp[0], 16, 16, xln, xz, xm, xmT, xdbl, part, ybuf, tbuf, cpart2, stream);
    run_vss(t_a, xr,  vp[1], 16, 16, xln, xz, xm, xmT, xdbl, part, ybuf, tbuf, cpart2, stream);

    // ---- down 0: 16 -> 8 (dwconv -> (pixel,c); pwconv as split-K GEMM) ----
    k_dwconv_s2_bn_gelu<<<(B_ * C_ * 64 + 255) / 256, 256, 0, stream>>>(
        xr, ds_dw, ds_bn1s, ds_bn1b, p1preT, 16, 16);
    {
        int M = B_ * 64;                 // 256 pixels
        dim3 g(C_ / 64, M / 64, KSPL);
        k_gemm_part<<<g, 256, 0, stream>>>(p1preT, ds_pw, cpart2, M, C_, C_);
        k_pw_fin<<<(M * C_ + 255) / 256, 256, 0, stream>>>(cpart2, ds_bn2s, ds_bn2b, p1, M, 64);
    }
    // ---- down 1: 8 -> 4 ----
    k_dwconv_s2_bn_gelu<<<(B_ * C_ * 16 + 255) / 256, 256, 0, stream>>>(
        p1, ds_dw + (size_t)C_ * 9, ds_bn1s + C_, ds_bn1b + C_, p2preT, 8, 8);
    {
        int M = B_ * 16;                 // 64 pixels
        dim3 g(C_ / 64, M / 64, KSPL);
        k_gemm_part<<<g, 256, 0, stream>>>(p2preT, ds_pw + (size_t)C_ * C_, cpart2, M, C_, C_);
        k_pw_fin<<<(M * C_ + 255) / 256, 256, 0, stream>>>(cpart2, ds_bn2s + C_, ds_bn2b + C_, p2, M, 16);
    }

    // ---- per-scale VSS ----
    run_vss(xr, proc0, vp[2], 16, 16, xln, xz, xm, xmT, xdbl, part, ybuf, tbuf, cpart2, stream);
    run_vss(p1, proc1, vp[3],  8,  8, xln, xz, xm, xmT, xdbl, part, ybuf, tbuf, cpart2, stream);
    run_vss(p2, proc2, vp[4],  4,  4, xln, xz, xm, xmT, xdbl, part, ybuf, tbuf, cpart2, stream);

    // ---- fuse i=1: up(proc2: 4->8) + proc1, resblk j=0 (8x8, N=256) ----
    k_up_add<<<(B_ * C_ * 64 + 255) / 256, 256, 0, stream>>>(proc2, proc1, up1t, 4, 4, 8, 8);
    {
        int Nn = B_ * 64;
        int tot = Nn * KC9;
        int tfin = C_ * Nn;
        dim3 gg(Nn / 64, C_ / 64, KSPL);
        k_im2col<<<(tot + 255) / 256, 256, 0, stream>>>(up1t, icol, 8, 8);
        k_gemm_conv_part<<<gg, 256, 0, stream>>>(fus_c1, icol, cpart2, Nn);
        k_conv_fin2<0><<<(tfin + 255) / 256, 256, 0, stream>>>(cpart2, fus_bn1s, fus_bn1b,
                                                               nullptr, rbh1, Nn, 64,
                                                               nullptr, nullptr);
        k_im2col<<<(tot + 255) / 256, 256, 0, stream>>>(rbh1, icol, 8, 8);
        k_gemm_conv_part<<<gg, 256, 0, stream>>>(fus_c2, icol, cpart2, Nn);
        k_conv_fin2<1><<<(tfin + 255) / 256, 256, 0, stream>>>(cpart2, fus_bn2s, fus_bn2b,
                                                               up1t, fus1, Nn, 64,
                                                               nullptr, nullptr);
    }
    // ---- fuse i=0: up(fus1: 8->16) + proc0, resblk j=1 (16x16, N=1024) ----
    // Second fin uses CM3: resblk epilogue + head bn0+gelu fused -> hbuf.
    k_up_add<<<(B_ * C_ * 256 + 255) / 256, 256, 0, stream>>>(fus1, proc0, up0t, 8, 8, 16, 16);
    {
        int Nn = B_ * 256;
        int tot = Nn * KC9;
        int tfin = C_ * Nn;
        dim3 gg(Nn / 64, C_ / 64, KSPL);
        k_im2col<<<(tot + 255) / 256, 256, 0, stream>>>(up0t, icol, 16, 16);
        k_gemm_conv_part<<<gg, 256, 0, stream>>>(fus_c1 + (size_t)C_ * KC9, icol, cpart2, Nn);
        k_conv_fin2<0><<<(tfin + 255) / 256, 256, 0, stream>>>(cpart2, fus_bn1s + C_, fus_bn1b + C_,
                                                               nullptr, rbh0, Nn, 256,
                                                               nullptr, nullptr);
        k_im2col<<<(tot + 255) / 256, 256, 0, stream>>>(rbh0, icol, 16, 16);
        k_gemm_conv_part<<<gg, 256, 0, stream>>>(fus_c2 + (size_t)C_ * KC9, icol, cpart2, Nn);
        k_conv_fin2<3><<<(tfin + 255) / 256, 256, 0, stream>>>(cpart2, fus_bn2s + C_, fus_bn2b + C_,
                                                               up0t, hbuf, Nn, 256,
                                                               op_bn0s, op_bn0b);
    }

    // ---- output head (bn0+gelu already fused into CM3 above) ----
    {
        int Nn = B_ * 256;
        int tot = Nn * KC9;
        int tfin = C_ * Nn;
        dim3 gg(Nn / 64, C_ / 64, KSPL);
        k_im2col<<<(tot + 255) / 256, 256, 0, stream>>>(hbuf, icol, 16, 16);
        k_gemm_conv_part<<<gg, 256, 0, stream>>>(op_conv, icol, cpart2, Nn);
        k_conv_fin2<2><<<(tfin + 255) / 256, 256, 0, stream>>>(cpart2, op_bn1s, op_bn1b,
                                                               x, (float*)d_out, Nn, 256,
                                                               nullptr, nullptr);
    }
    (void)in_sizes; (void)n_in; (void)out_size;
}